// Round 1
// baseline (342.804 us; speedup 1.0000x reference)
//
#include <hip/hip_runtime.h>

typedef _Float16 half8 __attribute__((ext_vector_type(8)));
typedef float f32x4 __attribute__((ext_vector_type(4)));

#define SEQ   4096
#define DIN   512
#define HID   1024
#define KMEM  256
#define NB    8
#define KC    768        // KMEM + DIN
#define VP    4352       // padded length of each phase copy of reversed u
#define OUT_H_ELEMS 33554432ull   // 8*4096*1024

__device__ __forceinline__ void load_lds16(const void* g, void* l) {
  __builtin_amdgcn_global_load_lds(
      (const __attribute__((address_space(1))) unsigned int*)g,
      (__attribute__((address_space(3))) unsigned int*)l, 16, 0, 0);
}

// ---------------- u = relu(x . W_u + b); emit xh (fp16) and v2 ----------------
// (unchanged from previous round)
__global__ __launch_bounds__(256) void u_kernel(
    const float* __restrict__ x, const float* __restrict__ Wu,
    const float* __restrict__ Wub,
    const float* __restrict__ Hf, const float* __restrict__ Wf,
    _Float16* __restrict__ xh, _Float16* __restrict__ v2,
    _Float16* __restrict__ Hh, _Float16* __restrict__ Wh)
{
  int tid_g = blockIdx.x * 256 + threadIdx.x;      // 0..2097151
  if (tid_g < KMEM * SEQ) Hh[tid_g] = (_Float16)Hf[tid_g];
  if (tid_g < HID * KC)   Wh[tid_g] = (_Float16)Wf[tid_g];
  if (tid_g < NB * 8 * 256) {                      // v2 pad zero
    int b2 = tid_g >> 11, rem = tid_g & 2047, p = rem >> 8, z = rem & 255;
    int t = (z < p) ? z : 4096 + z;                // [0,p) U [4096+p, 4352)
    v2[((size_t)b2 * 8 + p) * VP + t] = (_Float16)0.f;
  }

  int w = threadIdx.x >> 6, lane = threadIdx.x & 63;
  int row = blockIdx.x * 4 + w;               // 0..32767  (= b*4096 + s)
  const float4* xr = (const float4*)(x + (size_t)row * DIN);
  const float4* wr = (const float4*)Wu;
  float4 a0 = xr[lane * 2], a1 = xr[lane * 2 + 1];
  float4 w0 = wr[lane * 2], w1 = wr[lane * 2 + 1];
  float dot = a0.x * w0.x + a0.y * w0.y + a0.z * w0.z + a0.w * w0.w
            + a1.x * w1.x + a1.y * w1.y + a1.z * w1.z + a1.w * w1.w;
  half8 hv;
  hv[0] = (_Float16)a0.x; hv[1] = (_Float16)a0.y;
  hv[2] = (_Float16)a0.z; hv[3] = (_Float16)a0.w;
  hv[4] = (_Float16)a1.x; hv[5] = (_Float16)a1.y;
  hv[6] = (_Float16)a1.z; hv[7] = (_Float16)a1.w;
  *((half8*)(xh + (size_t)row * DIN + lane * 8)) = hv;
  #pragma unroll
  for (int off = 32; off > 0; off >>= 1) dot += __shfl_xor(dot, off);
  float u = dot + Wub[0];
  u = u > 0.f ? u : 0.f;
  if (lane < 8) {
    int s = row & (SEQ - 1), b = row >> 12;
    v2[(size_t)b * 8 * VP + (size_t)lane * VP + (4095 - s + lane)] = (_Float16)u;
  }
}

// ---------------- conv: m[b,s,k] = sum_{r=0..s} u[b,s-r] * H[k,r] ----------------
// (unchanged from previous round)
__global__ __launch_bounds__(256) void conv_kernel(
    const _Float16* __restrict__ Hh, const _Float16* __restrict__ v2,
    _Float16* __restrict__ mh)
{
  __shared__ _Float16 Bs[2][128 * 32];  // [col][r-chunk], stride 32
  __shared__ _Float16 Aw[2][8 * 104];   // 8 phase copies of the u-window
  int cb = blockIdx.x;                  // 0..15
  int b = cb >> 1, kt = cb & 1;
  int by = blockIdx.y;                  // 0..63
  int its = (by & 1) ? (63 - (by >> 1)) : (by >> 1);  // interleave heavy/light
  int s0 = its * 64, k0 = kt * 128;
  int tid = threadIdx.x;
  int w = tid >> 6, lane = tid & 63;
  int wr = w >> 1, wc = w & 1;
  int lm = lane & 15, q = lane >> 4;
  const _Float16* v2b = v2 + (size_t)b * 8 * VP;
  int gbase0 = 4032 - s0;               // window start at r0=0 (8-aligned, >=0)

  int aoffs[2];
  #pragma unroll
  for (int mi = 0; mi < 2; mi++) {
    int X = wr * 32 + mi * 16 + lm;     // s-offset within tile (0..63)
    int p = (X + 1) & 7;                // phase making the read 16B-aligned
    aoffs[mi] = p * 104 + (63 - X + p) + q * 8;
  }
  int boffs[4];
  #pragma unroll
  for (int ni = 0; ni < 4; ni++)
    boffs[ni] = (wc * 64 + ni * 16 + lm) * 32 + q * 8;

  int ap = tid / 13, aidx = tid - ap * 13;   // A staging map (104 x 16B chunks)

  f32x4 acc[2][4] = {};
  int iters = 2 * (its + 1);

  // preload iter 0 into buf 0
  {
    if (tid < 104)
      load_lds16(v2b + (size_t)ap * VP + gbase0 + aidx * 8, Aw[0] + tid * 8);
    #pragma unroll
    for (int p2 = 0; p2 < 2; p2++) {
      int c = p2 * 256 + tid;
      int col = c >> 2, ch = c & 3;
      load_lds16(Hh + (size_t)(k0 + col) * SEQ + ch * 8, Bs[0] + (size_t)c * 8);
    }
  }

  for (int it = 0; it < iters; ++it) {
    int buf = it & 1;
    __syncthreads();                    // vmcnt(0): buf's loads landed
    if (it + 1 < iters) {               // prefetch next chunk into buf^1
      int r0 = (it + 1) * 32;
      if (tid < 104)
        load_lds16(v2b + (size_t)ap * VP + gbase0 + r0 + aidx * 8, Aw[buf ^ 1] + tid * 8);
      #pragma unroll
      for (int p2 = 0; p2 < 2; p2++) {
        int c = p2 * 256 + tid;
        int col = c >> 2, ch = c & 3;
        load_lds16(Hh + (size_t)(k0 + col) * SEQ + r0 + ch * 8, Bs[buf ^ 1] + (size_t)c * 8);
      }
    }
    half8 af[2], bf[4];
    #pragma unroll
    for (int mi = 0; mi < 2; mi++) af[mi] = *((const half8*)(Aw[buf] + aoffs[mi]));
    #pragma unroll
    for (int ni = 0; ni < 4; ni++) bf[ni] = *((const half8*)(Bs[buf] + boffs[ni]));
    #pragma unroll
    for (int mi = 0; mi < 2; mi++)
      #pragma unroll
      for (int ni = 0; ni < 4; ni++)
        acc[mi][ni] = __builtin_amdgcn_mfma_f32_16x16x32_f16(af[mi], bf[ni], acc[mi][ni], 0, 0, 0);
  }
  size_t rowbase = (size_t)b * SEQ;
  #pragma unroll
  for (int mi = 0; mi < 2; mi++) {
    #pragma unroll
    for (int ni = 0; ni < 4; ni++) {
      int kout = k0 + wc * 64 + ni * 16 + lm;
      #pragma unroll
      for (int r = 0; r < 4; r++) {
        int sout = s0 + wr * 32 + mi * 16 + q * 4 + r;
        mh[(rowbase + sout) * KMEM + kout] = (_Float16)acc[mi][ni][r];
      }
    }
  }
}

// ---------------- h = relu([m, x] . W_h^T + b); also h[:, -1, :] tail ----------------
// NEW: 256x256 tile, 8 waves (512 thr), 4-deep LDS pipeline (4 bufs x 32KB),
// counted vmcnt (never 0 in steady state), per-phase raw barriers + setprio.
// K-step = 32 (one MFMA-K). Buffers: kstep k reads buf k&3; during kstep k we
// stage kstep k+3 into buf (k+3)&3 == (k-1)&3, whose reads finished at the
// trailing barrier of kstep k-1 -> no read/write race. vmcnt(8) at the end of
// each kstep leaves exactly the last two stage-groups (8 loads/lane) in flight,
// guaranteeing kstep k+1's data has landed. LDS rows are 64B: fragment reads
// (row*64B + q*16B) cover all 32 banks uniformly -> conflict-free, no swizzle.
__global__ __launch_bounds__(512, 2) void h_kernel(
    const _Float16* __restrict__ mh, const _Float16* __restrict__ xh,
    const _Float16* __restrict__ Wh, const float* __restrict__ Whb,
    float* __restrict__ out)
{
  __shared__ _Float16 ldsA[4][8192];   // 4 bufs of [256 rows][32 halfs]
  __shared__ _Float16 ldsB[4][8192];

  int id = blockIdx.x;                 // 0..511, HW round-robins id%8 -> XCD
  int wgid = (id & 7) * 64 + (id >> 3);      // bijective (512 % 8 == 0)
  int mt = wgid >> 2, nt = wgid & 3;         // XCD x owns mt in [x*16, x*16+16)

  int tid = threadIdx.x;
  int w = tid >> 6, lane = tid & 63;
  int wr = w >> 2, wc = w & 3;               // 2(M) x 4(N) waves, 128x64 each
  int lm = lane & 15, q = lane >> 4;

  // per-lane staging source offsets (chunk c = r*512+tid; row=c>>2, j=c&3)
  size_t offAm[2], offAx[2], offB[2];
  #pragma unroll
  for (int r = 0; r < 2; ++r) {
    int c = r * 512 + tid;
    int row = c >> 2, j = c & 3;
    offAm[r] = ((size_t)mt * 256 + row) * KMEM + j * 8;
    offAx[r] = ((size_t)mt * 256 + row) * DIN  + j * 8;
    offB[r]  = ((size_t)nt * 256 + row) * KC   + j * 8;
  }

#define STAGE_ROUND(kk, rr) do {                                              \
    int kb_ = (kk) * 32;                                                      \
    int c_ = (rr) * 512 + tid;                                                \
    const _Float16* sa_ = (kb_ < KMEM) ? (mh + offAm[rr] + kb_)               \
                                       : (xh + offAx[rr] + (kb_ - KMEM));     \
    load_lds16(sa_, &ldsA[(kk) & 3][c_ * 8]);                                 \
    load_lds16(Wh + offB[rr] + kb_, &ldsB[(kk) & 3][c_ * 8]);                 \
  } while (0)

  f32x4 acc[8][4] = {};

  // prologue: stage ksteps 0,1,2 (12 loads/lane); wait for kstep 0 (drop to 8)
  #pragma unroll
  for (int kk = 0; kk < 3; ++kk) { STAGE_ROUND(kk, 0); STAGE_ROUND(kk, 1); }
  asm volatile("s_waitcnt vmcnt(8)" ::: "memory");
  __builtin_amdgcn_s_barrier();
  asm volatile("" ::: "memory");

  for (int k = 0; k < 24; ++k) {             // 24 ksteps of K=32
    const _Float16* la = ldsA[k & 3];
    const _Float16* lb = ldsB[k & 3];
    half8 bf[4];
    #pragma unroll
    for (int qd = 0; qd < 2; ++qd) {         // 2 phases: mi 0-3, mi 4-7
      half8 af[4];
      #pragma unroll
      for (int m2 = 0; m2 < 4; ++m2)
        af[m2] = *((const half8*)(la + (wr * 128 + (qd * 4 + m2) * 16 + lm) * 32 + q * 8));
      if (qd == 0) {
        #pragma unroll
        for (int ni = 0; ni < 4; ++ni)
          bf[ni] = *((const half8*)(lb + (wc * 64 + ni * 16 + lm) * 32 + q * 8));
      }
      if (k < 21) STAGE_ROUND(k + 3, qd);    // 2 loads/lane/phase -> buf (k-1)&3

      asm volatile("" ::: "memory");
      __builtin_amdgcn_s_barrier();
      asm volatile("" ::: "memory");

      __builtin_amdgcn_s_setprio(1);
      #pragma unroll
      for (int m2 = 0; m2 < 4; ++m2)
        #pragma unroll
        for (int ni = 0; ni < 4; ++ni)
          acc[qd * 4 + m2][ni] = __builtin_amdgcn_mfma_f32_16x16x32_f16(
              af[m2], bf[ni], acc[qd * 4 + m2][ni], 0, 0, 0);
      __builtin_amdgcn_s_setprio(0);

      if (qd == 1) {
        // drain the stage-group carrying kstep k+1's data; keep last 2 groups
        if (k < 21)      asm volatile("s_waitcnt vmcnt(8)" ::: "memory");
        else if (k == 21) asm volatile("s_waitcnt vmcnt(4)" ::: "memory");
        else              asm volatile("s_waitcnt vmcnt(0)" ::: "memory");
      }
      asm volatile("" ::: "memory");
      __builtin_amdgcn_s_barrier();
      asm volatile("" ::: "memory");
    }
  }
#undef STAGE_ROUND

  // epilogue: bias + relu + store fp32 (+ last-timestep tail)
  #pragma unroll
  for (int ni = 0; ni < 4; ++ni) {
    int colg = nt * 256 + wc * 64 + ni * 16 + lm;
    float bias = Whb[colg];
    #pragma unroll
    for (int mi = 0; mi < 8; ++mi) {
      #pragma unroll
      for (int r = 0; r < 4; ++r) {
        int rowg = mt * 256 + wr * 128 + mi * 16 + q * 4 + r;
        float v = acc[mi][ni][r] + bias;
        v = v > 0.f ? v : 0.f;
        out[(size_t)rowg * HID + colg] = v;
        if ((rowg & (SEQ - 1)) == SEQ - 1)
          out[OUT_H_ELEMS + (size_t)(rowg >> 12) * HID + colg] = v;
      }
    }
  }
}

extern "C" void kernel_launch(void* const* d_in, const int* in_sizes, int n_in,
                              void* d_out, int out_size, void* d_ws, size_t ws_size,
                              hipStream_t stream) {
  const float* x   = (const float*)d_in[0];   // (8, 4096, 512)
  const float* Wu  = (const float*)d_in[1];   // (1, 512)
  const float* Wub = (const float*)d_in[2];   // (1,)
  const float* Whw = (const float*)d_in[3];   // (1024, 768)
  const float* Whb = (const float*)d_in[4];   // (1024,)
  const float* Hf  = (const float*)d_in[5];   // (256, 4096)
  float* out = (float*)d_out;

  char* ws = (char*)d_ws;
  _Float16* Hh = (_Float16*)(ws);                         // 2,097,152 B
  _Float16* Wh = (_Float16*)(ws + 2097152);               // 1,572,864 B
  _Float16* v2 = (_Float16*)(ws + 3670016);               //   557,056 B
  _Float16* xh = (_Float16*)(ws + 4227072);               // 33,554,432 B
  _Float16* mh = (_Float16*)(ws + 37781504);              // 16,777,216 B  (end 54,558,720)

  u_kernel<<<dim3(8192), dim3(256), 0, stream>>>(x, Wu, Wub, Hf, Whw, xh, v2, Hh, Wh);
  conv_kernel<<<dim3(16, 64), dim3(256), 0, stream>>>(Hh, v2, mh);
  h_kernel<<<dim3(512), dim3(512), 0, stream>>>(mh, xh, Wh, Whb, out);
}

// Round 2
// 327.217 us; speedup vs baseline: 1.0476x; 1.0476x over previous
//
#include <hip/hip_runtime.h>

typedef _Float16 half8 __attribute__((ext_vector_type(8)));
typedef float f32x4 __attribute__((ext_vector_type(4)));

#define SEQ   4096
#define DIN   512
#define HID   1024
#define KMEM  256
#define NB    8
#define KC    768        // KMEM + DIN
#define VP    4352       // padded length of each phase copy of reversed u
#define OUT_H_ELEMS 33554432ull   // 8*4096*1024

__device__ __forceinline__ void load_lds16(const void* g, void* l) {
  __builtin_amdgcn_global_load_lds(
      (const __attribute__((address_space(1))) unsigned int*)g,
      (__attribute__((address_space(3))) unsigned int*)l, 16, 0, 0);
}

// ---------------- u = relu(x . W_u + b); emit xh (fp16) and v2 ----------------
// (unchanged)
__global__ __launch_bounds__(256) void u_kernel(
    const float* __restrict__ x, const float* __restrict__ Wu,
    const float* __restrict__ Wub,
    const float* __restrict__ Hf, const float* __restrict__ Wf,
    _Float16* __restrict__ xh, _Float16* __restrict__ v2,
    _Float16* __restrict__ Hh, _Float16* __restrict__ Wh)
{
  int tid_g = blockIdx.x * 256 + threadIdx.x;      // 0..2097151
  if (tid_g < KMEM * SEQ) Hh[tid_g] = (_Float16)Hf[tid_g];
  if (tid_g < HID * KC)   Wh[tid_g] = (_Float16)Wf[tid_g];
  if (tid_g < NB * 8 * 256) {                      // v2 pad zero
    int b2 = tid_g >> 11, rem = tid_g & 2047, p = rem >> 8, z = rem & 255;
    int t = (z < p) ? z : 4096 + z;                // [0,p) U [4096+p, 4352)
    v2[((size_t)b2 * 8 + p) * VP + t] = (_Float16)0.f;
  }

  int w = threadIdx.x >> 6, lane = threadIdx.x & 63;
  int row = blockIdx.x * 4 + w;               // 0..32767  (= b*4096 + s)
  const float4* xr = (const float4*)(x + (size_t)row * DIN);
  const float4* wr = (const float4*)Wu;
  float4 a0 = xr[lane * 2], a1 = xr[lane * 2 + 1];
  float4 w0 = wr[lane * 2], w1 = wr[lane * 2 + 1];
  float dot = a0.x * w0.x + a0.y * w0.y + a0.z * w0.z + a0.w * w0.w
            + a1.x * w1.x + a1.y * w1.y + a1.z * w1.z + a1.w * w1.w;
  half8 hv;
  hv[0] = (_Float16)a0.x; hv[1] = (_Float16)a0.y;
  hv[2] = (_Float16)a0.z; hv[3] = (_Float16)a0.w;
  hv[4] = (_Float16)a1.x; hv[5] = (_Float16)a1.y;
  hv[6] = (_Float16)a1.z; hv[7] = (_Float16)a1.w;
  *((half8*)(xh + (size_t)row * DIN + lane * 8)) = hv;
  #pragma unroll
  for (int off = 32; off > 0; off >>= 1) dot += __shfl_xor(dot, off);
  float u = dot + Wub[0];
  u = u > 0.f ? u : 0.f;
  if (lane < 8) {
    int s = row & (SEQ - 1), b = row >> 12;
    v2[(size_t)b * 8 * VP + (size_t)lane * VP + (4095 - s + lane)] = (_Float16)u;
  }
}

// ---------------- conv: m[b,s,k] = sum_{r=0..s} u[b,s-r] * H[k,r] ----------------
// NEW: block tile 128s x 128k, 4 waves of 64x64 (4x4 frags): 16 MFMAs per
// 8 ds_read_b128 (0.5 KB LDS-read/MFMA, was 0.75). K-chunk 64 (half the
// barriers). 512 blocks; block g and g+256 (same CU) get complementary
// stripes -> every CU does exactly 66 K64-iterations (no makespan tail).
// Dispatch round-robin puts kt = XCD&1 -> each XCD L2-caches one 1MB H half.
// B LDS stride is 128B -> T2 XOR-swizzle (rule #21): linear gload_lds dest,
// inverse-swizzled global source (slot ^ col&7), same XOR on ds_read addr.
__global__ __launch_bounds__(256, 3) void conv_kernel(
    const _Float16* __restrict__ Hh, const _Float16* __restrict__ v2,
    _Float16* __restrict__ mh)
{
  __shared__ _Float16 Bs[2][128 * 64];  // [col][r-chunk 64], swizzled slots
  __shared__ _Float16 Aw[2][8 * 208];   // 8 phase copies of the u-window
  int g = blockIdx.x;                   // 0..511
  int cb = g & 15;
  int b = cb >> 1, kt = cb & 1;
  int jj = g >> 4;                      // 0..31
  int its = (jj < 16) ? jj : (47 - jj); // complement pairing: g vs g+256
  int s0 = its * 128, k0 = kt * 128;
  int tid = threadIdx.x;
  int w = tid >> 6, lane = tid & 63;
  int wr = w >> 1, wc = w & 1;
  int lm = lane & 15, q = lane >> 4;
  const _Float16* v2b = v2 + (size_t)b * 8 * VP;
  int gb = 3968 - s0;                   // window start at r0=0 (>=0, 8-aligned)

  // loop-invariant A-frag LDS offsets (phase p makes each read 16B-aligned)
  int aoffs[4];
  #pragma unroll
  for (int mi = 0; mi < 4; mi++) {
    int X = wr * 64 + mi * 16 + lm;     // s-offset within tile (0..127)
    int p = (X + 1) & 7;
    aoffs[mi] = p * 208 + (127 - X + p) + q * 8;
  }
  // B-frag offsets, kq=0 slot = q ^ (lm&7); kq=1 adds ^32 elements
  int boffs[4];
  #pragma unroll
  for (int ni = 0; ni < 4; ni++) {
    int col = wc * 64 + ni * 16 + lm;
    boffs[ni] = col * 64 + ((q ^ (lm & 7)) << 3);
  }

  int ap = tid / 26, aidx = tid - ap * 26;   // A staging map (208 x 16B chunks)

  f32x4 acc[4][4] = {};
  int iters = 2 * (its + 1);            // K64 chunks to cover r in [0, s0+128)

  // preload iter 0 into buf 0
  {
    if (tid < 208)
      load_lds16(v2b + (size_t)ap * VP + gb + aidx * 8, Aw[0] + tid * 8);
    #pragma unroll
    for (int p2 = 0; p2 < 4; p2++) {
      int c = p2 * 256 + tid;
      int col = c >> 3, sl = c & 7;
      load_lds16(Hh + (size_t)(k0 + col) * SEQ + ((sl ^ (col & 7)) << 3),
                 Bs[0] + (size_t)c * 8);
    }
  }

  for (int it = 0; it < iters; ++it) {
    int buf = it & 1;
    __syncthreads();                    // vmcnt(0): buf's loads landed
    if (it + 1 < iters) {               // prefetch next K64 chunk into buf^1
      int r0 = (it + 1) * 64;
      if (tid < 208)
        load_lds16(v2b + (size_t)ap * VP + gb + r0 + aidx * 8, Aw[buf ^ 1] + tid * 8);
      #pragma unroll
      for (int p2 = 0; p2 < 4; p2++) {
        int c = p2 * 256 + tid;
        int col = c >> 3, sl = c & 7;
        load_lds16(Hh + (size_t)(k0 + col) * SEQ + r0 + ((sl ^ (col & 7)) << 3),
                   Bs[buf ^ 1] + (size_t)c * 8);
      }
    }
    #pragma unroll
    for (int kq = 0; kq < 2; kq++) {
      half8 af[4], bf[4];
      #pragma unroll
      for (int mi = 0; mi < 4; mi++)
        af[mi] = *((const half8*)(Aw[buf] + aoffs[mi] + kq * 32));
      #pragma unroll
      for (int ni = 0; ni < 4; ni++)
        bf[ni] = *((const half8*)(Bs[buf] + (boffs[ni] ^ (kq << 5))));
      #pragma unroll
      for (int mi = 0; mi < 4; mi++)
        #pragma unroll
        for (int ni = 0; ni < 4; ni++)
          acc[mi][ni] = __builtin_amdgcn_mfma_f32_16x16x32_f16(af[mi], bf[ni], acc[mi][ni], 0, 0, 0);
    }
  }
  // epilogue: write m in fp16 (input to the h-GEMM)
  size_t rowbase = (size_t)b * SEQ;
  #pragma unroll
  for (int mi = 0; mi < 4; mi++) {
    #pragma unroll
    for (int ni = 0; ni < 4; ni++) {
      int kout = k0 + wc * 64 + ni * 16 + lm;
      #pragma unroll
      for (int r = 0; r < 4; r++) {
        int sout = s0 + wr * 64 + mi * 16 + q * 4 + r;
        mh[(rowbase + sout) * KMEM + kout] = (_Float16)acc[mi][ni][r];
      }
    }
  }
}

// ---------------- h = relu([m, x] . W_h^T + b); also h[:, -1, :] tail ----------------
// Reverted to the proven round-0 128x128 version.
__global__ __launch_bounds__(256) void h_kernel(
    const _Float16* __restrict__ mh, const _Float16* __restrict__ xh,
    const _Float16* __restrict__ Wh, const float* __restrict__ Whb,
    float* __restrict__ out)
{
  __shared__ _Float16 As[2][128 * 32];
  __shared__ _Float16 Bs[2][128 * 32];
  int id = blockIdx.y * 8 + blockIdx.x;   // dispatch-linear id (x fastest)
  int xcd = id & 7;
  int j = id >> 3;
  int mt = (j >> 3) * 8 + xcd;            // 0..255: mt-groups pinned per XCD
  int nt = j & 7;
  int tid = threadIdx.x, w = tid >> 6, lane = tid & 63;
  int wr = w >> 1, wc = w & 1, lm = lane & 15, q = lane >> 4;

  f32x4 acc[4][4] = {};
  // preload iter 0 into buf 0
  {
    #pragma unroll
    for (int p2 = 0; p2 < 2; p2++) {
      int c = p2 * 256 + tid;
      int row = c >> 2, ch = c & 3;
      size_t rg = (size_t)mt * 128 + row;
      load_lds16(mh + rg * KMEM + ch * 8, As[0] + (size_t)c * 8);
      load_lds16(Wh + (size_t)(nt * 128 + row) * KC + ch * 8, Bs[0] + (size_t)c * 8);
    }
  }
  for (int it = 0; it < 24; ++it) {
    int buf = it & 1;
    __syncthreads();
    if (it + 1 < 24) {
      int kk = (it + 1) * 32;
      #pragma unroll
      for (int p2 = 0; p2 < 2; p2++) {
        int c = p2 * 256 + tid;
        int row = c >> 2, ch = c & 3;
        size_t rg = (size_t)mt * 128 + row;
        const _Float16* srcA = (kk < KMEM)
            ? (mh + rg * KMEM + kk + ch * 8)
            : (xh + rg * DIN + (kk - KMEM) + ch * 8);
        load_lds16(srcA, As[buf ^ 1] + (size_t)c * 8);
        load_lds16(Wh + (size_t)(nt * 128 + row) * KC + kk + ch * 8,
                   Bs[buf ^ 1] + (size_t)c * 8);
      }
    }
    half8 af[4], bf[4];
    #pragma unroll
    for (int mi = 0; mi < 4; mi++)
      af[mi] = *((const half8*)(As[buf] + (wr * 64 + mi * 16 + lm) * 32 + q * 8));
    #pragma unroll
    for (int ni = 0; ni < 4; ni++)
      bf[ni] = *((const half8*)(Bs[buf] + (wc * 64 + ni * 16 + lm) * 32 + q * 8));
    #pragma unroll
    for (int mi = 0; mi < 4; mi++)
      #pragma unroll
      for (int ni = 0; ni < 4; ni++)
        acc[mi][ni] = __builtin_amdgcn_mfma_f32_16x16x32_f16(af[mi], bf[ni], acc[mi][ni], 0, 0, 0);
  }
  // epilogue: bias + relu + store fp32 (+ last-timestep tail)
  #pragma unroll
  for (int ni = 0; ni < 4; ni++) {
    int colg = nt * 128 + wc * 64 + ni * 16 + lm;
    float bias = Whb[colg];
    #pragma unroll
    for (int mi = 0; mi < 4; mi++) {
      #pragma unroll
      for (int r = 0; r < 4; r++) {
        int rowg = mt * 128 + wr * 64 + mi * 16 + q * 4 + r;
        float v = acc[mi][ni][r] + bias;
        v = v > 0.f ? v : 0.f;
        out[(size_t)rowg * HID + colg] = v;
        if ((rowg & (SEQ - 1)) == SEQ - 1)
          out[OUT_H_ELEMS + (size_t)(rowg >> 12) * HID + colg] = v;
      }
    }
  }
}

extern "C" void kernel_launch(void* const* d_in, const int* in_sizes, int n_in,
                              void* d_out, int out_size, void* d_ws, size_t ws_size,
                              hipStream_t stream) {
  const float* x   = (const float*)d_in[0];   // (8, 4096, 512)
  const float* Wu  = (const float*)d_in[1];   // (1, 512)
  const float* Wub = (const float*)d_in[2];   // (1,)
  const float* Whw = (const float*)d_in[3];   // (1024, 768)
  const float* Whb = (const float*)d_in[4];   // (1024,)
  const float* Hf  = (const float*)d_in[5];   // (256, 4096)
  float* out = (float*)d_out;

  char* ws = (char*)d_ws;
  _Float16* Hh = (_Float16*)(ws);                         // 2,097,152 B
  _Float16* Wh = (_Float16*)(ws + 2097152);               // 1,572,864 B
  _Float16* v2 = (_Float16*)(ws + 3670016);               //   557,056 B
  _Float16* xh = (_Float16*)(ws + 4227072);               // 33,554,432 B
  _Float16* mh = (_Float16*)(ws + 37781504);              // 16,777,216 B  (end 54,558,720)

  u_kernel<<<dim3(8192), dim3(256), 0, stream>>>(x, Wu, Wub, Hf, Whw, xh, v2, Hh, Wh);
  conv_kernel<<<dim3(512), dim3(256), 0, stream>>>(Hh, v2, mh);
  h_kernel<<<dim3(8, 256), dim3(256), 0, stream>>>(mh, xh, Wh, Whb, out);
}